// Round 10
// baseline (346.226 us; speedup 1.0000x reference)
//
#include <hip/hip_runtime.h>
#include <math.h>

#define DIM   128
#define SLICE (DIM*DIM)       // 16384
#define VOL   (DIM*DIM*DIM)   // 2097152
#define NK    4
#define NVOL  8
#define SSTR  33              // staging row stride in float4

// Gaussian taps exp(-x^2/(2*5^2)), x=-4..4 (unnormalized, matches reference)
__constant__ float c_g[9] = {
    0.72614904f, 0.83527021f, 0.92311635f, 0.98019867f, 1.0f,
    0.98019867f, 0.92311635f, 0.83527021f, 0.72614904f
};

// ws layout (floats): [0..7] sumP per vol, [8..15] sumIP per vol,
//                     [16..19] num per class, [20..23] den per class

// K1: pure-stream sums. 1024 blocks x 20 float4 loads/thread, direct atomics
// (8 per block onto 16 addresses -> negligible serialization).
__global__ __launch_bounds__(256) void k_sums(
    const float* __restrict__ labels, const float* __restrict__ inputs,
    float* __restrict__ red)
{
    const int b     = blockIdx.x >> 9;
    const int chunk = blockIdx.x & 511;
    const int t     = threadIdx.x;
    const size_t off4 = (size_t)chunk*1024 + t;
    const float4* __restrict__ I4 = (const float4*)inputs + (size_t)b*(VOL/4) + off4;
    const float4* __restrict__ L4 = (const float4*)labels;
    float sp[4] = {0,0,0,0}, sip[4] = {0,0,0,0};
    #pragma unroll
    for (int j = 0; j < 4; ++j) {
        const float4 iv = I4[j*256];
        #pragma unroll
        for (int k = 0; k < 4; ++k) {
            const float4 p = L4[(size_t)(b*NK + k)*(VOL/4) + off4 + j*256];
            sp[k]  += p.x + p.y + p.z + p.w;
            sip[k] += p.x*iv.x + p.y*iv.y + p.z*iv.z + p.w*iv.w;
        }
    }
    #pragma unroll
    for (int k = 0; k < 4; ++k) {
        #pragma unroll
        for (int o = 32; o; o >>= 1) {
            sp[k]  += __shfl_down(sp[k],  o);
            sip[k] += __shfl_down(sip[k], o);
        }
    }
    __shared__ float sB[8][4];
    const int wid = t >> 6;
    if ((t & 63) == 0) {
        #pragma unroll
        for (int k = 0; k < 4; ++k) { sB[k][wid] = sp[k]; sB[4+k][wid] = sip[k]; }
    }
    __syncthreads();
    if (t < 8) {
        const float v = sB[t][0] + sB[t][1] + sB[t][2] + sB[t][3];
        atomicAdd(&red[(t < 4 ? 0 : 8) + b*NK + (t & 3)], v);
    }
}

// K2: fused wh-blur + d-blur + weights + reduction, PAIR-STAGED:
// 2 d-slices per __syncthreads (4 LDS buffers, 20 barriers per block instead
// of 40). Next-pair window loads issue before the barrier -> 2-slice-deep
// prefetch across the drain. Grid 512: (vol 8) x (strip 16) x (d-quarter 4).
__global__ __launch_bounds__(256, 4) void k_fused(
    const float* __restrict__ labels, const float* __restrict__ inputs,
    const float* __restrict__ red, float* __restrict__ nd)
{
    __shared__ float4 sW[4][16*SSTR];     // 33792 B
    __shared__ float sN[4], sD[4];

    const int dq    = blockIdx.x & 3;
    const int strip = (blockIdx.x >> 2) & 15;
    const int vol   = blockIdx.x >> 6;
    const int b = vol >> 2, kcls = vol & 3;
    const int d0 = dq * 32;
    const int t  = threadIdx.x;
    const float g1 = c_g[5], g2 = c_g[6], g3 = c_g[7], g4 = c_g[8];
    const float4 z4 = make_float4(0.f, 0.f, 0.f, 0.f);

    const float* __restrict__ src = labels + (size_t)vol*VOL;
    const float mean = red[8+vol] / (red[vol] + 20.97152f);

    // two staged row-sites per thread: rows r0 (0..7) and r0+8, col c0
    const int r0 = t >> 5, c0 = t & 31;
    // h-blur / output site: global row strip*8+ho, float4 col wq
    const int ho = t >> 5, wq = t & 31;

    const int hA = strip*8 - 4 + r0;
    const int hB = strip*8 + 4 + r0;
    const bool vA = (unsigned)hA < 128u;
    const bool vB = (unsigned)hB < 128u;
    const float4* __restrict__ rowA = (const float4*)(src + (size_t)(vA ? hA : 0)*DIM);
    const float4* __restrict__ rowB = (const float4*)(src + (size_t)(vB ? hB : 0)*DIM);

    const size_t ob4 = (size_t)(strip*8 + ho)*(DIM/4) + wq;
    const float4* __restrict__ P4 = (const float4*)src + ob4;
    const float4* __restrict__ I4 = (const float4*)(inputs + (size_t)b*VOL) + ob4;

    auto winA = [&](int s, float4& pv, float4& cv, float4& nx) {
        pv = cv = nx = z4;
        if (vA && (unsigned)s < 128u) {
            const float4* rp = rowA + (size_t)s*(SLICE/4);
            cv = rp[c0];
            if (c0 > 0)  pv = rp[c0-1];
            if (c0 < 31) nx = rp[c0+1];
        }
    };
    auto winB = [&](int s, float4& pv, float4& cv, float4& nx) {
        pv = cv = nx = z4;
        if (vB && (unsigned)s < 128u) {
            const float4* rp = rowB + (size_t)s*(SLICE/4);
            cv = rp[c0];
            if (c0 > 0)  pv = rp[c0-1];
            if (c0 < 31) nx = rp[c0+1];
        }
    };
    auto wblur = [&](const float4& pv, const float4& cv, const float4& nx) -> float4 {
        float4 o;
        o.x = cv.x + g1*(pv.w+cv.y) + g2*(pv.z+cv.z) + g3*(pv.y+cv.w) + g4*(pv.x+nx.x);
        o.y = cv.y + g1*(cv.x+cv.z) + g2*(pv.w+cv.w) + g3*(pv.z+nx.x) + g4*(pv.y+nx.y);
        o.z = cv.z + g1*(cv.y+cv.w) + g2*(cv.x+nx.x) + g3*(pv.w+nx.y) + g4*(pv.z+nx.z);
        o.w = cv.w + g1*(cv.z+nx.x) + g2*(cv.y+nx.y) + g3*(cv.x+nx.z) + g4*(pv.w+nx.w);
        return o;
    };
    auto hblur = [&](int buf) -> float4 {
        float4 acc = sW[buf][(ho+4)*SSTR + wq];
        #pragma unroll
        for (int dt = 1; dt <= 4; ++dt) {
            const float g = c_g[4+dt];
            const float4 u = sW[buf][(ho+4-dt)*SSTR + wq];
            const float4 v = sW[buf][(ho+4+dt)*SSTR + wq];
            acc.x += g*(u.x+v.x); acc.y += g*(u.y+v.y);
            acc.z += g*(u.z+v.z); acc.w += g*(u.w+v.w);
        }
        return acc;
    };

    float4 ring[10];
    #pragma unroll
    for (int i = 0; i < 10; ++i) ring[i] = z4;
    float numAcc = 0.f, denAcc = 0.f;

    // window regs for current pair (slices s0, s0+1)
    float4 a0p,a0c,a0n, a1p,a1c,a1n, b0p,b0c,b0n, b1p,b1c,b1n;
    winA(d0-4, a0p,a0c,a0n);  winA(d0-3, a1p,a1c,a1n);
    winB(d0-4, b0p,b0c,b0n);  winB(d0-3, b1p,b1c,b1n);

    for (int p = 0; p < 20; ++p) {
        const int s0 = d0 - 4 + 2*p;
        const int buf0 = (p & 1)*2, buf1 = buf0 + 1;
        // stage both slices (consumes window regs)
        sW[buf0][r0*SSTR + c0]     = wblur(a0p,a0c,a0n);
        sW[buf1][r0*SSTR + c0]     = wblur(a1p,a1c,a1n);
        sW[buf0][(r0+8)*SSTR + c0] = wblur(b0p,b0c,b0n);
        sW[buf1][(r0+8)*SSTR + c0] = wblur(b1p,b1c,b1n);
        // issue next pair's window loads (fly across the barrier wait)
        if (p < 19) {
            winA(s0+2, a0p,a0c,a0n);  winA(s0+3, a1p,a1c,a1n);
            winB(s0+2, b0p,b0c,b0n);  winB(s0+3, b1p,b1c,b1n);
        }
        // output-voxel P, I for dcur0 = s0-4, dcur1 = s0-3
        float4 pc0 = z4, ic0 = z4, pc1 = z4, ic1 = z4;
        const bool outStep = (p >= 4);
        if (outStep) {
            pc0 = P4[(size_t)(s0-4)*(SLICE/4)];  ic0 = I4[(size_t)(s0-4)*(SLICE/4)];
            pc1 = P4[(size_t)(s0-3)*(SLICE/4)];  ic1 = I4[(size_t)(s0-3)*(SLICE/4)];
        }
        __syncthreads();                   // one barrier per 2 slices
        const float4 acc0 = hblur(buf0);
        const float4 acc1 = hblur(buf1);
        #pragma unroll
        for (int i = 0; i < 8; ++i) ring[i] = ring[i+2];
        ring[8] = acc0;  ring[9] = acc1;
        if (outStep) {
            float4 B0 = ring[4], B1 = ring[5];
            #pragma unroll
            for (int dt = 1; dt <= 4; ++dt) {
                const float g = c_g[4+dt];
                B0.x += g*(ring[4+dt].x + ring[4-dt].x);
                B0.y += g*(ring[4+dt].y + ring[4-dt].y);
                B0.z += g*(ring[4+dt].z + ring[4-dt].z);
                B0.w += g*(ring[4+dt].w + ring[4-dt].w);
                B1.x += g*(ring[5+dt].x + ring[5-dt].x);
                B1.y += g*(ring[5+dt].y + ring[5-dt].y);
                B1.z += g*(ring[5+dt].z + ring[5-dt].z);
                B1.w += g*(ring[5+dt].w + ring[5-dt].w);
            }
            { float df = ic0.x - mean; df *= df; const float bw = B0.x * __expf(-df*df); numAcc += bw*pc0.x; denAcc += bw; }
            { float df = ic0.y - mean; df *= df; const float bw = B0.y * __expf(-df*df); numAcc += bw*pc0.y; denAcc += bw; }
            { float df = ic0.z - mean; df *= df; const float bw = B0.z * __expf(-df*df); numAcc += bw*pc0.z; denAcc += bw; }
            { float df = ic0.w - mean; df *= df; const float bw = B0.w * __expf(-df*df); numAcc += bw*pc0.w; denAcc += bw; }
            { float df = ic1.x - mean; df *= df; const float bw = B1.x * __expf(-df*df); numAcc += bw*pc1.x; denAcc += bw; }
            { float df = ic1.y - mean; df *= df; const float bw = B1.y * __expf(-df*df); numAcc += bw*pc1.y; denAcc += bw; }
            { float df = ic1.z - mean; df *= df; const float bw = B1.z * __expf(-df*df); numAcc += bw*pc1.z; denAcc += bw; }
            { float df = ic1.w - mean; df *= df; const float bw = B1.w * __expf(-df*df); numAcc += bw*pc1.w; denAcc += bw; }
        }
    }

    #pragma unroll
    for (int o = 32; o; o >>= 1) { numAcc += __shfl_down(numAcc, o); denAcc += __shfl_down(denAcc, o); }
    if ((t & 63) == 0) { sN[t >> 6] = numAcc; sD[t >> 6] = denAcc; }
    __syncthreads();
    if (t == 0) {
        atomicAdd(&nd[kcls],   sN[0]+sN[1]+sN[2]+sN[3]);
        atomicAdd(&nd[4+kcls], sD[0]+sD[1]+sD[2]+sD[3]);
    }
}

__global__ void k_final(const float* __restrict__ red, float* __restrict__ out)
{
    float loss = 0.f;
    #pragma unroll
    for (int k = 0; k < 4; ++k) loss += fabsf(red[16+k] / (red[20+k] + 1e-6f));
    out[0] = (float)NK - loss;
}

extern "C" void kernel_launch(void* const* d_in, const int* in_sizes, int n_in,
                              void* d_out, int out_size, void* d_ws, size_t ws_size,
                              hipStream_t stream)
{
    const float* labels = (const float*)d_in[0];   // (2,4,128,128,128)
    const float* inputs = (const float*)d_in[1];   // (2,1,128,128,128)
    float* out = (float*)d_out;
    float* red = (float*)d_ws;                     // 24 floats

    hipMemsetAsync(red, 0, 24*sizeof(float), stream);
    k_sums<<<2*512, 256, 0, stream>>>(labels, inputs, red);
    k_fused<<<NVOL*16*4, 256, 0, stream>>>(labels, inputs, red, red + 16);
    k_final<<<1, 1, 0, stream>>>(red, out);
}